// Round 1
// baseline (675.792 us; speedup 1.0000x reference)
//
#include <hip/hip_runtime.h>

#define INPUT_SIZE 32768
#define NUM_COLS   4096
#define NUM_ACTIVE 82

// Kernel A: boosted overlap = (connections @ input) * boost.
// One block per minicolumn row; 256 threads stream the 128 KB row with
// float4 coalesced loads (16 B/lane). Sums of 0/1 products are exact
// integers in fp32, so result is bit-exact vs numpy in any order.
__global__ __launch_bounds__(256) void matvec_boost_kernel(
    const float* __restrict__ conn, const float* __restrict__ input,
    const float* __restrict__ boost, float* __restrict__ overlap)
{
    const int c = blockIdx.x;
    const int t = threadIdx.x;
    const float4* row = (const float4*)(conn + (size_t)c * INPUT_SIZE);
    const float4* in4 = (const float4*)input;

    // 32768/4 = 8192 float4 per row; 256 threads -> 32 iterations.
    float acc0 = 0.f, acc1 = 0.f;
    #pragma unroll
    for (int k = 0; k < INPUT_SIZE / 4 / 256; k += 2) {
        float4 a0 = row[t + 256 * k];
        float4 b0 = in4[t + 256 * k];
        float4 a1 = row[t + 256 * (k + 1)];
        float4 b1 = in4[t + 256 * (k + 1)];
        acc0 += a0.x * b0.x + a0.y * b0.y + a0.z * b0.z + a0.w * b0.w;
        acc1 += a1.x * b1.x + a1.y * b1.y + a1.z * b1.z + a1.w * b1.w;
    }
    float acc = acc0 + acc1;

    // wave64 shuffle reduce
    #pragma unroll
    for (int off = 32; off > 0; off >>= 1)
        acc += __shfl_down(acc, off, 64);

    __shared__ float part[4];
    const int wave = t >> 6;
    if ((t & 63) == 0) part[wave] = acc;
    __syncthreads();
    if (t == 0) {
        float tot = part[0] + part[1] + part[2] + part[3];
        overlap[c] = tot * boost[c];
    }
}

// Kernel B: exact stable top-k membership. One wave per column.
// rank(c) = #{ j : v_j > v_c  OR  (v_j == v_c AND j < c) }  (strict total
// order == jax.lax.top_k / stable-argsort tie-break: lowest index wins).
// active iff rank < 82. Writes both output halves.
__global__ __launch_bounds__(64) void topk_mask_kernel(
    const float* __restrict__ vals, float* __restrict__ out)
{
    const int c = blockIdx.x;
    const int lane = threadIdx.x;
    const float v = vals[c];
    const float4* v4 = (const float4*)vals;

    int cnt = 0;
    #pragma unroll
    for (int k = 0; k < NUM_COLS / 4 / 64; ++k) {   // 16 iterations
        const int i4 = lane + 64 * k;
        float4 b = v4[i4];
        const int j = i4 * 4;
        cnt += (b.x > v) || (b.x == v && (j + 0) < c);
        cnt += (b.y > v) || (b.y == v && (j + 1) < c);
        cnt += (b.z > v) || (b.z == v && (j + 2) < c);
        cnt += (b.w > v) || (b.w == v && (j + 3) < c);
    }
    #pragma unroll
    for (int off = 32; off > 0; off >>= 1)
        cnt += __shfl_down(cnt, off, 64);

    if (lane == 0) {
        const bool act = cnt < NUM_ACTIVE;
        out[c] = act ? 1.0f : 0.0f;
        out[NUM_COLS + c] = act ? v : 0.0f;
    }
}

extern "C" void kernel_launch(void* const* d_in, const int* in_sizes, int n_in,
                              void* d_out, int out_size, void* d_ws, size_t ws_size,
                              hipStream_t stream) {
    const float* input = (const float*)d_in[0];   // [32768]
    const float* conn  = (const float*)d_in[1];   // [4096, 32768]
    const float* boost = (const float*)d_in[2];   // [4096]
    float* out = (float*)d_out;                   // [8192]: mask then masked-boosted
    float* ov  = (float*)d_ws;                    // [4096] boosted overlaps

    matvec_boost_kernel<<<NUM_COLS, 256, 0, stream>>>(conn, input, boost, ov);
    topk_mask_kernel<<<NUM_COLS, 64, 0, stream>>>(ov, out);
}

// Round 2
// 649.915 us; speedup vs baseline: 1.0398x; 1.0398x over previous
//
#include <hip/hip_runtime.h>

#define INPUT_SIZE 32768
#define NUM_COLS   4096
#define NUM_ACTIVE 82
#define ROWS_PER_BLOCK 4
#define NF4 (INPUT_SIZE / 4)   // 8192 float4 per row

typedef float v4f __attribute__((ext_vector_type(4)));

__device__ __forceinline__ float dot4(v4f a, v4f b) {
    return a.x * b.x + a.y * b.y + a.z * b.z + a.w * b.w;
}

// Kernel A: boosted overlap = (connections @ input) * boost.
// 4 rows per block, 256 threads, grid=1024 (16 waves/CU). Each input float4
// is loaded once and reused for 4 rows (register reuse); conn rows are
// streamed once with nontemporal loads. Sums of 0/1 products are exact
// integers in fp32 -> bit-exact vs numpy in any summation order.
__global__ __launch_bounds__(256) void matvec_boost_kernel(
    const float* __restrict__ conn, const float* __restrict__ input,
    const float* __restrict__ boost, float* __restrict__ overlap)
{
    const int r0 = blockIdx.x * ROWS_PER_BLOCK;
    const int t  = threadIdx.x;
    const v4f* in4 = (const v4f*)input;
    const v4f* row0 = (const v4f*)(conn + (size_t)(r0 + 0) * INPUT_SIZE);
    const v4f* row1 = (const v4f*)(conn + (size_t)(r0 + 1) * INPUT_SIZE);
    const v4f* row2 = (const v4f*)(conn + (size_t)(r0 + 2) * INPUT_SIZE);
    const v4f* row3 = (const v4f*)(conn + (size_t)(r0 + 3) * INPUT_SIZE);

    float acc[ROWS_PER_BLOCK] = {0.f, 0.f, 0.f, 0.f};

    // 8192 float4 / 256 threads = 32 slots/thread; process 2 slots per iter.
    for (int k = t; k < NF4; k += 512) {
        const int k2 = k + 256;
        v4f b0 = in4[k];
        v4f b1 = in4[k2];
        v4f a00 = __builtin_nontemporal_load(&row0[k]);
        v4f a01 = __builtin_nontemporal_load(&row0[k2]);
        v4f a10 = __builtin_nontemporal_load(&row1[k]);
        v4f a11 = __builtin_nontemporal_load(&row1[k2]);
        v4f a20 = __builtin_nontemporal_load(&row2[k]);
        v4f a21 = __builtin_nontemporal_load(&row2[k2]);
        v4f a30 = __builtin_nontemporal_load(&row3[k]);
        v4f a31 = __builtin_nontemporal_load(&row3[k2]);
        acc[0] += dot4(a00, b0) + dot4(a01, b1);
        acc[1] += dot4(a10, b0) + dot4(a11, b1);
        acc[2] += dot4(a20, b0) + dot4(a21, b1);
        acc[3] += dot4(a30, b0) + dot4(a31, b1);
    }

    // wave64 shuffle reduce each accumulator
    #pragma unroll
    for (int r = 0; r < ROWS_PER_BLOCK; ++r) {
        float a = acc[r];
        #pragma unroll
        for (int off = 32; off > 0; off >>= 1)
            a += __shfl_down(a, off, 64);
        acc[r] = a;
    }

    __shared__ float part[4][ROWS_PER_BLOCK];
    const int wave = t >> 6;
    if ((t & 63) == 0) {
        #pragma unroll
        for (int r = 0; r < ROWS_PER_BLOCK; ++r) part[wave][r] = acc[r];
    }
    __syncthreads();
    if (t < ROWS_PER_BLOCK) {
        float tot = part[0][t] + part[1][t] + part[2][t] + part[3][t];
        overlap[r0 + t] = tot * boost[r0 + t];
    }
}

// Kernel B: exact stable top-k membership. One wave per column.
// rank(c) = #{ j : v_j > v_c  OR  (v_j == v_c AND j < c) } — matches
// jax.lax.top_k's lowest-index tie-break. active iff rank < 82.
__global__ __launch_bounds__(64) void topk_mask_kernel(
    const float* __restrict__ vals, float* __restrict__ out)
{
    const int c = blockIdx.x;
    const int lane = threadIdx.x;
    const float v = vals[c];
    const float4* v4 = (const float4*)vals;

    int cnt = 0;
    #pragma unroll
    for (int k = 0; k < NUM_COLS / 4 / 64; ++k) {   // 16 iterations
        const int i4 = lane + 64 * k;
        float4 b = v4[i4];
        const int j = i4 * 4;
        cnt += (b.x > v) || (b.x == v && (j + 0) < c);
        cnt += (b.y > v) || (b.y == v && (j + 1) < c);
        cnt += (b.z > v) || (b.z == v && (j + 2) < c);
        cnt += (b.w > v) || (b.w == v && (j + 3) < c);
    }
    #pragma unroll
    for (int off = 32; off > 0; off >>= 1)
        cnt += __shfl_down(cnt, off, 64);

    if (lane == 0) {
        const bool act = cnt < NUM_ACTIVE;
        out[c] = act ? 1.0f : 0.0f;
        out[NUM_COLS + c] = act ? v : 0.0f;
    }
}

extern "C" void kernel_launch(void* const* d_in, const int* in_sizes, int n_in,
                              void* d_out, int out_size, void* d_ws, size_t ws_size,
                              hipStream_t stream) {
    const float* input = (const float*)d_in[0];   // [32768]
    const float* conn  = (const float*)d_in[1];   // [4096, 32768]
    const float* boost = (const float*)d_in[2];   // [4096]
    float* out = (float*)d_out;                   // [8192]: mask then masked-boosted
    float* ov  = (float*)d_ws;                    // [4096] boosted overlaps

    matvec_boost_kernel<<<NUM_COLS / ROWS_PER_BLOCK, 256, 0, stream>>>(conn, input, boost, ov);
    topk_mask_kernel<<<NUM_COLS, 64, 0, stream>>>(ov, out);
}